// Round 1
// baseline (281.413 us; speedup 1.0000x reference)
//
#include <hip/hip_runtime.h>
#include <hip/hip_bf16.h>
#include <stdint.h>

#define B_ 4
#define S_ 2048
#define D_ 1024
#define H_ 16
#define DH_ 64
#define BH_ 64
#define M_ 8192   // B_*S_

typedef __bf16 bf16;
typedef __attribute__((ext_vector_type(8))) __bf16 bf16x8;
typedef __attribute__((ext_vector_type(4))) float f32x4;
typedef __attribute__((ext_vector_type(8))) float f32x8;

__device__ inline void gload16(const void* g, void* l) {
  __builtin_amdgcn_global_load_lds((const __attribute__((address_space(1))) void*)g,
                                   (__attribute__((address_space(3))) void*)l, 16, 0, 0);
}

// ---------------- 1. fp32 -> bf16 convert of q/k/v ----------------
__global__ __launch_bounds__(256) void k_conv(const float* __restrict__ q,
    const float* __restrict__ k, const float* __restrict__ v, bf16* __restrict__ o) {
  int z = blockIdx.y;
  const float* s = z == 0 ? q : (z == 1 ? k : v);
  bf16* d = o + (size_t)z * ((size_t)M_ * D_);
  int n8 = M_ * D_ / 8;
  for (int i = blockIdx.x * 256 + threadIdx.x; i < n8; i += gridDim.x * 256) {
    f32x8 f = ((const f32x8*)s)[i];
    bf16x8 b;
#pragma unroll
    for (int j = 0; j < 8; j++) b[j] = (bf16)f[j];
    ((bf16x8*)d)[i] = b;
  }
}

// ---------------- 2. W (DxD fp32) -> W^T (bf16) ----------------
__global__ __launch_bounds__(256) void k_wt(const float* __restrict__ wq,
    const float* __restrict__ wk, const float* __restrict__ wv, bf16* __restrict__ o) {
  __shared__ float t[32][33];
  int z = blockIdx.z;
  const float* w = z == 0 ? wq : (z == 1 ? wk : wv);
  bf16* d = o + (size_t)z * D_ * D_;
  int bn = blockIdx.x * 32;  // col (n) of W
  int bk = blockIdx.y * 32;  // row (k) of W
  int tx = threadIdx.x & 31, ty = threadIdx.x >> 5;  // 32 x 8
#pragma unroll
  for (int j = 0; j < 32; j += 8) t[ty + j][tx] = w[(size_t)(bk + ty + j) * D_ + bn + tx];
  __syncthreads();
#pragma unroll
  for (int j = 0; j < 32; j += 8)
    d[(size_t)(bn + ty + j) * D_ + bk + tx] = (bf16)t[tx][ty + j];
}

// ---------------- 3. projection GEMM: X(8192x1024) @ W -> per-head layout ----
// 128x128 tile, BK=64, 4 waves each 64x64. LDS linear-staged via global_load_lds
// with pre-swizzled global source; reads XOR-swizzled (T2 both-sides pattern).
__global__ __launch_bounds__(256) void k_proj(const bf16* __restrict__ X,
    const bf16* __restrict__ WT, bf16* __restrict__ Qo, bf16* __restrict__ Ko,
    bf16* __restrict__ Vo) {
  __shared__ bf16 lds[16384];  // A tile [128][64] elems [0,8192), B tile [8192,16384)
  int z = blockIdx.z;
  const char* Ab = (const char*)(X + (size_t)z * M_ * D_);
  const char* Bb = (const char*)(WT + (size_t)z * D_ * D_);
  int m0 = blockIdx.x * 128, n0 = blockIdx.y * 128;
  int tid = threadIdx.x, lane = tid & 63, w = tid >> 6;
  int wr = w >> 1, wc = w & 1, fr = lane & 15, fg = lane >> 4;
  f32x4 acc[4][4];
#pragma unroll
  for (int a = 0; a < 4; a++)
#pragma unroll
    for (int b = 0; b < 4; b++) acc[a][b] = (f32x4){0.f, 0.f, 0.f, 0.f};

  for (int k0 = 0; k0 < D_; k0 += 64) {
#pragma unroll
    for (int it = 0; it < 8; ++it) {
      int ow = (w + 4 * it) * 1024;   // wave-uniform LDS byte offset
      int o = ow + lane * 16;         // this lane's byte slot
      const char* src;
      if (o < 16384) {                // A region
        int row = o >> 7;
        int db = (o & 127) ^ ((row & 7) << 4);
        src = Ab + (size_t)(m0 + row) * 2048 + k0 * 2 + db;
      } else {                        // B region
        int lo = o - 16384, row = lo >> 7;
        int db = (lo & 127) ^ ((row & 7) << 4);
        src = Bb + (size_t)(n0 + row) * 2048 + k0 * 2 + db;
      }
      gload16(src, (char*)lds + ow);
    }
    __syncthreads();
#pragma unroll
    for (int c = 0; c < 2; c++) {
      bf16x8 af[4], bfr[4];
#pragma unroll
      for (int mi = 0; mi < 4; mi++) {
        int row = wr * 64 + mi * 16 + fr;
        af[mi] = *(const bf16x8*)&lds[row * 64 + ((fg * 8 + 32 * c) ^ ((row & 7) << 3))];
      }
#pragma unroll
      for (int ni = 0; ni < 4; ni++) {
        int row = wc * 64 + ni * 16 + fr;
        bfr[ni] = *(const bf16x8*)&lds[8192 + row * 64 + ((fg * 8 + 32 * c) ^ ((row & 7) << 3))];
      }
#pragma unroll
      for (int mi = 0; mi < 4; mi++)
#pragma unroll
        for (int ni = 0; ni < 4; ni++)
          acc[mi][ni] = __builtin_amdgcn_mfma_f32_16x16x32_bf16(af[mi], bfr[ni],
                                                                acc[mi][ni], 0, 0, 0);
    }
    __syncthreads();
  }
  bf16* O = z == 0 ? Qo : (z == 1 ? Ko : Vo);
  float sc = (z == 0) ? 0.125f : 1.0f;  // fold 1/sqrt(dh) into Q (pow2 -> exact)
#pragma unroll
  for (int mi = 0; mi < 4; mi++)
#pragma unroll
    for (int r = 0; r < 4; r++) {
      int row = m0 + wr * 64 + mi * 16 + 4 * fg + r;
      int b = row >> 11, s = row & 2047;
#pragma unroll
      for (int ni = 0; ni < 4; ni++) {
        int col = n0 + wc * 64 + ni * 16 + fr;
        int h = col >> 6, d = col & 63;
        O[((size_t)(b * H_ + h) * S_ + s) * DH_ + d] = (bf16)(acc[mi][ni][r] * sc);
      }
    }
}

// ---------------- 4. V [bh][s][64] -> V^T [bh][64][s] ----------------
__global__ __launch_bounds__(256) void k_vt(const bf16* __restrict__ V, bf16* __restrict__ VT) {
  __shared__ bf16 t[64][72];
  int bh = blockIdx.y, st = blockIdx.x * 64;
  int tid = threadIdx.x;
#pragma unroll
  for (int p = 0; p < 2; p++) {
    int idx = tid + p * 256;
    int s = idx >> 3, d0 = (idx & 7) * 8;
    *(bf16x8*)&t[s][d0] = *(const bf16x8*)(V + ((size_t)bh * S_ + st + s) * DH_ + d0);
  }
  __syncthreads();
#pragma unroll
  for (int p = 0; p < 2; p++) {
    int idx = tid + p * 256;
    int d = idx >> 3, s0 = (idx & 7) * 8;
    bf16x8 r;
#pragma unroll
    for (int j = 0; j < 8; j++) r[j] = t[s0 + j][d];
    *(bf16x8*)(VT + ((size_t)bh * DH_ + d) * S_ + st + s0) = r;
  }
}

// ---------------- 5. flash attention ----------------
// grid (S/128, BH). 4 waves x 32 q-rows. KBLK=64. K,V^T tiles LDS-staged
// swizzled; online softmax fp32; P via per-wave swizzled LDS -> PV A-frags.
__global__ __launch_bounds__(256) void k_attn(const bf16* __restrict__ Q,
    const bf16* __restrict__ Kt, const bf16* __restrict__ VT, float* __restrict__ out) {
  __shared__ bf16 kv[8192];     // K tile [64][64] bytes [0,8192) ; V^T tile [8192,16384)
  __shared__ bf16 sP[4][2048];  // per wave [32 rows][64 keys], XOR-swizzled
  int qt = blockIdx.x, bh = blockIdx.y;
  int b = bh >> 4, h = bh & 15;
  int tid = threadIdx.x, lane = tid & 63, w = tid >> 6;
  int fr = lane & 15, fg = lane >> 4;
  const char* Kb = (const char*)(Kt + (size_t)bh * S_ * DH_);
  const char* Vb = (const char*)(VT + (size_t)bh * DH_ * S_);
  int q0 = qt * 128 + w * 32;
  bf16x8 qf[2][2];
#pragma unroll
  for (int mi = 0; mi < 2; mi++)
#pragma unroll
    for (int c = 0; c < 2; c++)
      qf[mi][c] = *(const bf16x8*)(Q + ((size_t)bh * S_ + q0 + mi * 16 + fr) * DH_ + fg * 8 + 32 * c);
  float m_[2][4], l_[2][4];
  f32x4 o_[2][4];
#pragma unroll
  for (int mi = 0; mi < 2; mi++)
#pragma unroll
    for (int r = 0; r < 4; r++) { m_[mi][r] = -1e30f; l_[mi][r] = 0.f; }
#pragma unroll
  for (int mi = 0; mi < 2; mi++)
#pragma unroll
    for (int ds = 0; ds < 4; ds++) o_[mi][ds] = (f32x4){0.f, 0.f, 0.f, 0.f};

  for (int kt = 0; kt < S_ / 64; ++kt) {
#pragma unroll
    for (int it = 0; it < 4; ++it) {
      int ow = (w + 4 * it) * 1024;
      int o = ow + lane * 16;
      const char* src;
      if (o < 8192) {               // K tile
        int kk = o >> 7;
        int db = (o & 127) ^ ((kk & 7) << 4);
        src = Kb + (size_t)(kt * 64 + kk) * 128 + db;
      } else {                      // V^T tile
        int lo = o - 8192, d = lo >> 7;
        int db = (lo & 127) ^ ((d & 7) << 4);
        src = Vb + (size_t)d * (S_ * 2) + kt * 128 + db;
      }
      gload16(src, (char*)kv + ow);
    }
    __syncthreads();
    // QK^T : D[q][key] ; col=key=lane&15, row=q=4*fg+r
    f32x4 s_[2][4];
#pragma unroll
    for (int ks = 0; ks < 4; ks++) {
      bf16x8 kf[2];
#pragma unroll
      for (int c = 0; c < 2; c++) {
        int row = ks * 16 + fr;
        kf[c] = *(const bf16x8*)&kv[row * 64 + ((fg * 8 + 32 * c) ^ ((row & 7) << 3))];
      }
#pragma unroll
      for (int mi = 0; mi < 2; mi++) {
        f32x4 a = (f32x4){0.f, 0.f, 0.f, 0.f};
        a = __builtin_amdgcn_mfma_f32_16x16x32_bf16(qf[mi][0], kf[0], a, 0, 0, 0);
        a = __builtin_amdgcn_mfma_f32_16x16x32_bf16(qf[mi][1], kf[1], a, 0, 0, 0);
        s_[mi][ks] = a;
      }
    }
    // online softmax
#pragma unroll
    for (int mi = 0; mi < 2; mi++) {
      float tm[4];
#pragma unroll
      for (int r = 0; r < 4; r++) {
        float t0 = fmaxf(fmaxf(s_[mi][0][r], s_[mi][1][r]), fmaxf(s_[mi][2][r], s_[mi][3][r]));
#pragma unroll
        for (int dlt = 1; dlt < 16; dlt <<= 1) t0 = fmaxf(t0, __shfl_xor(t0, dlt));
        tm[r] = t0;
      }
#pragma unroll
      for (int r = 0; r < 4; r++) {
        float mn = fmaxf(m_[mi][r], tm[r]);
        float sf = __expf(m_[mi][r] - mn);
        m_[mi][r] = mn;
        l_[mi][r] *= sf;
#pragma unroll
        for (int ds = 0; ds < 4; ds++) o_[mi][ds][r] *= sf;
      }
#pragma unroll
      for (int ks = 0; ks < 4; ks++)
#pragma unroll
        for (int r = 0; r < 4; r++) {
          float p = __expf(s_[mi][ks][r] - m_[mi][r]);
          l_[mi][r] += p;
          int row = mi * 16 + 4 * fg + r;
          int key = fr + 16 * ks;
          sP[w][row * 64 + (key ^ ((row & 7) << 3))] = (bf16)p;
        }
    }
    // PV : O[q][d] += P x V
#pragma unroll
    for (int c = 0; c < 2; c++) {
      bf16x8 pa[2];
#pragma unroll
      for (int mi = 0; mi < 2; mi++) {
        int row = mi * 16 + fr;
        pa[mi] = *(const bf16x8*)&sP[w][row * 64 + ((fg * 8 + 32 * c) ^ ((row & 7) << 3))];
      }
#pragma unroll
      for (int ds = 0; ds < 4; ds++) {
        int row = ds * 16 + fr;
        bf16x8 vf = *(const bf16x8*)&kv[4096 + row * 64 + ((fg * 8 + 32 * c) ^ ((row & 7) << 3))];
#pragma unroll
        for (int mi = 0; mi < 2; mi++)
          o_[mi][ds] = __builtin_amdgcn_mfma_f32_16x16x32_bf16(pa[mi], vf, o_[mi][ds], 0, 0, 0);
      }
    }
    __syncthreads();
  }
  // finalize: reduce l across the 16 key-lanes, normalize, store fp32
#pragma unroll
  for (int mi = 0; mi < 2; mi++)
#pragma unroll
    for (int r = 0; r < 4; r++) {
      float t0 = l_[mi][r];
#pragma unroll
      for (int dlt = 1; dlt < 16; dlt <<= 1) t0 += __shfl_xor(t0, dlt);
      float inv = 1.0f / t0;
      int s = q0 + mi * 16 + 4 * fg + r;
#pragma unroll
      for (int ds = 0; ds < 4; ds++) {
        int col = h * DH_ + ds * 16 + fr;
        out[((size_t)b * S_ + s) * D_ + col] = o_[mi][ds][r] * inv;
      }
    }
}

extern "C" void kernel_launch(void* const* d_in, const int* in_sizes, int n_in,
                              void* d_out, int out_size, void* d_ws, size_t ws_size,
                              hipStream_t stream) {
  (void)in_sizes; (void)n_in; (void)out_size; (void)ws_size;
  const float* q  = (const float*)d_in[0];
  const float* k  = (const float*)d_in[1];
  const float* v  = (const float*)d_in[2];
  const float* wq = (const float*)d_in[3];
  const float* wk = (const float*)d_in[4];
  const float* wv = (const float*)d_in[5];
  float* out = (float*)d_out;
  char* ws = (char*)d_ws;
  size_t off = 0;
  bf16* xb = (bf16*)(ws + off); off += (size_t)3 * M_ * D_ * 2;    // 50.3 MB
  bf16* wt = (bf16*)(ws + off); off += (size_t)3 * D_ * D_ * 2;    //  6.3 MB
  bf16* Qw = (bf16*)(ws + off); off += (size_t)BH_ * S_ * DH_ * 2; // 16.8 MB
  bf16* Kw = (bf16*)(ws + off); off += (size_t)BH_ * S_ * DH_ * 2;
  bf16* Vw = (bf16*)(ws + off); off += (size_t)BH_ * S_ * DH_ * 2;
  bf16* Vt = (bf16*)(ws + off); off += (size_t)BH_ * S_ * DH_ * 2;

  k_conv<<<dim3(1024, 3), 256, 0, stream>>>(q, k, v, xb);
  k_wt  <<<dim3(32, 32, 3), 256, 0, stream>>>(wq, wk, wv, wt);
  k_proj<<<dim3(64, 8, 3), 256, 0, stream>>>(xb, wt, Qw, Kw, Vw);
  k_vt  <<<dim3(32, 64), 256, 0, stream>>>(Vw, Vt);
  k_attn<<<dim3(16, 64), 256, 0, stream>>>(Qw, Kw, Vt, out);
}

// Round 3
// 216.993 us; speedup vs baseline: 1.2969x; 1.2969x over previous
//
#include <hip/hip_runtime.h>
#include <hip/hip_bf16.h>
#include <stdint.h>

#define B_ 4
#define S_ 2048
#define D_ 1024
#define H_ 16
#define DH_ 64
#define BH_ 64
#define M_ 8192   // B_*S_

typedef __bf16 bf16;
typedef __attribute__((ext_vector_type(8))) __bf16 bf16x8;
typedef __attribute__((ext_vector_type(4))) float f32x4;
typedef __attribute__((ext_vector_type(8))) float f32x8;

#define EXP2F(x) __builtin_amdgcn_exp2f(x)

__device__ inline void gload16(const void* g, void* l) {
  __builtin_amdgcn_global_load_lds((const __attribute__((address_space(1))) void*)g,
                                   (__attribute__((address_space(3))) void*)l, 16, 0, 0);
}

// ---------------- 1. fp32 -> bf16 convert of q/k/v ----------------
__global__ __launch_bounds__(256) void k_conv(const float* __restrict__ q,
    const float* __restrict__ k, const float* __restrict__ v, bf16* __restrict__ o) {
  int z = blockIdx.y;
  const float* s = z == 0 ? q : (z == 1 ? k : v);
  bf16* d = o + (size_t)z * ((size_t)M_ * D_);
  int n8 = M_ * D_ / 8;
  for (int i = blockIdx.x * 256 + threadIdx.x; i < n8; i += gridDim.x * 256) {
    f32x8 f = ((const f32x8*)s)[i];
    bf16x8 b;
#pragma unroll
    for (int j = 0; j < 8; j++) b[j] = (bf16)f[j];
    ((bf16x8*)d)[i] = b;
  }
}

// ---------------- 2. W (DxD fp32) -> W^T (bf16) ----------------
__global__ __launch_bounds__(256) void k_wt(const float* __restrict__ wq,
    const float* __restrict__ wk, const float* __restrict__ wv, bf16* __restrict__ o) {
  __shared__ float t[32][33];
  int z = blockIdx.z;
  const float* w = z == 0 ? wq : (z == 1 ? wk : wv);
  bf16* d = o + (size_t)z * D_ * D_;
  int bn = blockIdx.x * 32;  // col (n) of W
  int bk = blockIdx.y * 32;  // row (k) of W
  int tx = threadIdx.x & 31, ty = threadIdx.x >> 5;  // 32 x 8
#pragma unroll
  for (int j = 0; j < 32; j += 8) t[ty + j][tx] = w[(size_t)(bk + ty + j) * D_ + bn + tx];
  __syncthreads();
#pragma unroll
  for (int j = 0; j < 32; j += 8)
    d[(size_t)(bn + ty + j) * D_ + bk + tx] = (bf16)t[tx][ty + j];
}

// ---------------- 3. projection GEMM: X(8192x1024) @ W -> per-head layout ----
__global__ __launch_bounds__(256) void k_proj(const bf16* __restrict__ X,
    const bf16* __restrict__ WT, bf16* __restrict__ Qo, bf16* __restrict__ Ko,
    bf16* __restrict__ Vo) {
  __shared__ bf16 lds[16384];  // A tile [128][64] elems [0,8192), B tile [8192,16384)
  int z = blockIdx.z;
  const char* Ab = (const char*)(X + (size_t)z * M_ * D_);
  const char* Bb = (const char*)(WT + (size_t)z * D_ * D_);
  int m0 = blockIdx.x * 128, n0 = blockIdx.y * 128;
  int tid = threadIdx.x, lane = tid & 63, w = tid >> 6;
  int wr = w >> 1, wc = w & 1, fr = lane & 15, fg = lane >> 4;
  f32x4 acc[4][4];
#pragma unroll
  for (int a = 0; a < 4; a++)
#pragma unroll
    for (int b = 0; b < 4; b++) acc[a][b] = (f32x4){0.f, 0.f, 0.f, 0.f};

  for (int k0 = 0; k0 < D_; k0 += 64) {
#pragma unroll
    for (int it = 0; it < 8; ++it) {
      int ow = (w + 4 * it) * 1024;   // wave-uniform LDS byte offset
      int o = ow + lane * 16;         // this lane's byte slot
      const char* src;
      if (o < 16384) {                // A region
        int row = o >> 7;
        int db = (o & 127) ^ ((row & 7) << 4);
        src = Ab + (size_t)(m0 + row) * 2048 + k0 * 2 + db;
      } else {                        // B region
        int lo = o - 16384, row = lo >> 7;
        int db = (lo & 127) ^ ((row & 7) << 4);
        src = Bb + (size_t)(n0 + row) * 2048 + k0 * 2 + db;
      }
      gload16(src, (char*)lds + ow);
    }
    __syncthreads();
#pragma unroll
    for (int c = 0; c < 2; c++) {
      bf16x8 af[4], bfr[4];
#pragma unroll
      for (int mi = 0; mi < 4; mi++) {
        int row = wr * 64 + mi * 16 + fr;
        af[mi] = *(const bf16x8*)&lds[row * 64 + ((fg * 8 + 32 * c) ^ ((row & 7) << 3))];
      }
#pragma unroll
      for (int ni = 0; ni < 4; ni++) {
        int row = wc * 64 + ni * 16 + fr;
        bfr[ni] = *(const bf16x8*)&lds[8192 + row * 64 + ((fg * 8 + 32 * c) ^ ((row & 7) << 3))];
      }
#pragma unroll
      for (int mi = 0; mi < 4; mi++)
#pragma unroll
        for (int ni = 0; ni < 4; ni++)
          acc[mi][ni] = __builtin_amdgcn_mfma_f32_16x16x32_bf16(af[mi], bfr[ni],
                                                                acc[mi][ni], 0, 0, 0);
    }
    __syncthreads();
  }
  bf16* O = z == 0 ? Qo : (z == 1 ? Ko : Vo);
  // Q: fold 1/sqrt(dh) AND log2(e) so softmax can use exp2 directly.
  float sc = (z == 0) ? 0.18033688011112042f : 1.0f;
#pragma unroll
  for (int mi = 0; mi < 4; mi++)
#pragma unroll
    for (int r = 0; r < 4; r++) {
      int row = m0 + wr * 64 + mi * 16 + 4 * fg + r;
      int b = row >> 11, s = row & 2047;
#pragma unroll
      for (int ni = 0; ni < 4; ni++) {
        int col = n0 + wc * 64 + ni * 16 + fr;
        int h = col >> 6, d = col & 63;
        O[((size_t)(b * H_ + h) * S_ + s) * DH_ + d] = (bf16)(acc[mi][ni][r] * sc);
      }
    }
}

// ---------------- 4. V [bh][s][64] -> sigma-permuted V^T [bh][64][s] --------
// Key order within each 64-block permuted by sigma: slot bits
// [c f1 f0 j2 j1 j0] -> key bits [c j2 f1 f0 j1 j0], so the attention kernel's
// PV A-fragment (P held lane-local after swapped QK^T) needs NO cross-lane ops.
__global__ __launch_bounds__(256) void k_vt(const bf16* __restrict__ V, bf16* __restrict__ VT) {
  __shared__ bf16 t[64][72];
  int bh = blockIdx.y, st = blockIdx.x * 64;
  int tid = threadIdx.x;
#pragma unroll
  for (int p = 0; p < 2; p++) {
    int idx = tid + p * 256;
    int s = idx >> 3, d0 = (idx & 7) * 8;
    *(bf16x8*)&t[s][d0] = *(const bf16x8*)(V + ((size_t)bh * S_ + st + s) * DH_ + d0);
  }
  __syncthreads();
#pragma unroll
  for (int p = 0; p < 2; p++) {
    int idx = tid + p * 256;
    int d = idx >> 3, s0 = (idx & 7) * 8;
    bf16x8 r;
#pragma unroll
    for (int j = 0; j < 8; j++) {
      int slot = s0 + j;
      int key = (slot & 0x23) | ((slot & 0x18) >> 1) | ((slot & 0x04) << 2);
      r[j] = t[key][d];
    }
    *(bf16x8*)(VT + ((size_t)bh * DH_ + d) * S_ + st + s0) = r;
  }
}

// ---------------- 5. flash attention (swapped QK^T, in-register P) ----------
// grid (S/128, BH). 4 waves x 32 q-rows. KBLK=64.
// st = mfma(K,Q): lane holds P-slice for q = lane&15, keys {16ks+4fg+r}.
// Softmax col-form: scalar m,l per (lane,mi); 2 shfl_xor for cross-fg max.
// PV A-frag = direct register repack (key permutation folded into k_vt).
__global__ __launch_bounds__(256) void k_attn(const bf16* __restrict__ Q,
    const bf16* __restrict__ Kt, const bf16* __restrict__ VT, float* __restrict__ out) {
  __shared__ bf16 kv[8192];     // 16KB: K tile [64][64] bytes [0,8192); V [8192,16384)
  int qt = blockIdx.x, bh = blockIdx.y;
  int b = bh >> 4, h = bh & 15;
  int tid = threadIdx.x, lane = tid & 63, w = tid >> 6;
  int fr = lane & 15, fg = lane >> 4;
  const char* Kb = (const char*)(Kt + (size_t)bh * S_ * DH_);
  const char* Vb = (const char*)(VT + (size_t)bh * DH_ * S_);
  int q0 = qt * 128 + w * 32;
  bf16x8 qf[2][2];
#pragma unroll
  for (int mi = 0; mi < 2; mi++)
#pragma unroll
    for (int c = 0; c < 2; c++)
      qf[mi][c] = *(const bf16x8*)(Q + ((size_t)bh * S_ + q0 + mi * 16 + fr) * DH_ + fg * 8 + 32 * c);
  float m_[2] = {-1e30f, -1e30f};
  float l_[2] = {0.f, 0.f};
  f32x4 o_[2][4];
#pragma unroll
  for (int mi = 0; mi < 2; mi++)
#pragma unroll
    for (int ds = 0; ds < 4; ds++) o_[mi][ds] = (f32x4){0.f, 0.f, 0.f, 0.f};

  for (int kt = 0; kt < S_ / 64; ++kt) {
#pragma unroll
    for (int it = 0; it < 4; ++it) {
      int ow = (w + 4 * it) * 1024;
      int o = ow + lane * 16;
      const char* src;
      if (o < 8192) {               // K tile
        int kk = o >> 7;
        int db = (o & 127) ^ ((kk & 7) << 4);
        src = Kb + (size_t)(kt * 64 + kk) * 128 + db;
      } else {                      // V^T tile (sigma already applied globally)
        int lo = o - 8192, d = lo >> 7;
        int db = (lo & 127) ^ ((d & 7) << 4);
        src = Vb + (size_t)d * (S_ * 2) + kt * 128 + db;
      }
      gload16(src, (char*)kv + ow);
    }
    __syncthreads();
    // swapped QK^T: st[mi][ks] = D[key][q], col=q=fr, row(key part)=4*fg+r
    f32x4 st[2][4];
    __builtin_amdgcn_s_setprio(1);
#pragma unroll
    for (int ks = 0; ks < 4; ks++) {
      bf16x8 kf[2];
#pragma unroll
      for (int c = 0; c < 2; c++) {
        int row = ks * 16 + fr;
        kf[c] = *(const bf16x8*)&kv[row * 64 + ((fg * 8 + 32 * c) ^ ((row & 7) << 3))];
      }
#pragma unroll
      for (int mi = 0; mi < 2; mi++) {
        f32x4 a = (f32x4){0.f, 0.f, 0.f, 0.f};
        a = __builtin_amdgcn_mfma_f32_16x16x32_bf16(kf[0], qf[mi][0], a, 0, 0, 0);
        a = __builtin_amdgcn_mfma_f32_16x16x32_bf16(kf[1], qf[mi][1], a, 0, 0, 0);
        st[mi][ks] = a;
      }
    }
    __builtin_amdgcn_s_setprio(0);
    // col-form online softmax (all in log2 domain; Q pre-scaled by log2e/8)
    bf16x8 pa[2][2];
#pragma unroll
    for (int mi = 0; mi < 2; mi++) {
      float mx = st[mi][0][0];
#pragma unroll
      for (int ks = 0; ks < 4; ks++)
#pragma unroll
        for (int r = 0; r < 4; r++) mx = fmaxf(mx, st[mi][ks][r]);
      mx = fmaxf(mx, __shfl_xor(mx, 16));
      mx = fmaxf(mx, __shfl_xor(mx, 32));
      float mnew = fmaxf(m_[mi], mx);
      float sf = EXP2F(m_[mi] - mnew);
      m_[mi] = mnew;
      float pe[4][4];
      float ps = 0.f;
#pragma unroll
      for (int ks = 0; ks < 4; ks++)
#pragma unroll
        for (int r = 0; r < 4; r++) {
          pe[ks][r] = EXP2F(st[mi][ks][r] - mnew);
          ps += pe[ks][r];
        }
      l_[mi] = l_[mi] * sf + ps;
      // rescale o_ (row-form): fetch sf for q-rows 4*fg+r from col-form lanes
      float s0 = __shfl(sf, 4 * fg + 0);
      float s1 = __shfl(sf, 4 * fg + 1);
      float s2 = __shfl(sf, 4 * fg + 2);
      float s3 = __shfl(sf, 4 * fg + 3);
#pragma unroll
      for (int ds = 0; ds < 4; ds++) {
        o_[mi][ds][0] *= s0; o_[mi][ds][1] *= s1;
        o_[mi][ds][2] *= s2; o_[mi][ds][3] *= s3;
      }
      // PV A-fragments: direct repack (sigma folded into V^T global layout)
      pa[mi][0] = (bf16x8){(bf16)pe[0][0], (bf16)pe[0][1], (bf16)pe[0][2], (bf16)pe[0][3],
                           (bf16)pe[1][0], (bf16)pe[1][1], (bf16)pe[1][2], (bf16)pe[1][3]};
      pa[mi][1] = (bf16x8){(bf16)pe[2][0], (bf16)pe[2][1], (bf16)pe[2][2], (bf16)pe[2][3],
                           (bf16)pe[3][0], (bf16)pe[3][1], (bf16)pe[3][2], (bf16)pe[3][3]};
    }
    // PV: O[q][d] += P x V
    __builtin_amdgcn_s_setprio(1);
#pragma unroll
    for (int c = 0; c < 2; c++) {
#pragma unroll
      for (int ds = 0; ds < 4; ds++) {
        int row = ds * 16 + fr;
        bf16x8 vf = *(const bf16x8*)&kv[4096 + row * 64 + ((fg * 8 + 32 * c) ^ ((row & 7) << 3))];
#pragma unroll
        for (int mi = 0; mi < 2; mi++)
          o_[mi][ds] = __builtin_amdgcn_mfma_f32_16x16x32_bf16(pa[mi][c], vf, o_[mi][ds], 0, 0, 0);
      }
    }
    __builtin_amdgcn_s_setprio(0);
    __syncthreads();
  }
  // finalize: l partial per fg-lane -> butterfly over fg; redistribute to rows
#pragma unroll
  for (int mi = 0; mi < 2; mi++) {
    float lf = l_[mi];
    lf += __shfl_xor(lf, 16);
    lf += __shfl_xor(lf, 32);
    float inv = 1.0f / lf;
    float ir[4];
#pragma unroll
    for (int r = 0; r < 4; r++) ir[r] = __shfl(inv, 4 * fg + r);
#pragma unroll
    for (int r = 0; r < 4; r++) {
      int s = q0 + mi * 16 + 4 * fg + r;
#pragma unroll
      for (int ds = 0; ds < 4; ds++) {
        int col = h * DH_ + ds * 16 + fr;
        out[((size_t)b * S_ + s) * D_ + col] = o_[mi][ds][r] * ir[r];
      }
    }
  }
}

extern "C" void kernel_launch(void* const* d_in, const int* in_sizes, int n_in,
                              void* d_out, int out_size, void* d_ws, size_t ws_size,
                              hipStream_t stream) {
  (void)in_sizes; (void)n_in; (void)out_size; (void)ws_size;
  const float* q  = (const float*)d_in[0];
  const float* k  = (const float*)d_in[1];
  const float* v  = (const float*)d_in[2];
  const float* wq = (const float*)d_in[3];
  const float* wk = (const float*)d_in[4];
  const float* wv = (const float*)d_in[5];
  float* out = (float*)d_out;
  char* ws = (char*)d_ws;
  size_t off = 0;
  bf16* xb = (bf16*)(ws + off); off += (size_t)3 * M_ * D_ * 2;    // 50.3 MB
  bf16* wt = (bf16*)(ws + off); off += (size_t)3 * D_ * D_ * 2;    //  6.3 MB
  bf16* Qw = (bf16*)(ws + off); off += (size_t)BH_ * S_ * DH_ * 2; // 16.8 MB
  bf16* Kw = (bf16*)(ws + off); off += (size_t)BH_ * S_ * DH_ * 2;
  bf16* Vw = (bf16*)(ws + off); off += (size_t)BH_ * S_ * DH_ * 2;
  bf16* Vt = (bf16*)(ws + off); off += (size_t)BH_ * S_ * DH_ * 2;

  k_conv<<<dim3(1024, 3), 256, 0, stream>>>(q, k, v, xb);
  k_wt  <<<dim3(32, 32, 3), 256, 0, stream>>>(wq, wk, wv, wt);
  k_proj<<<dim3(64, 8, 3), 256, 0, stream>>>(xb, wt, Qw, Kw, Vw);
  k_vt  <<<dim3(32, 64), 256, 0, stream>>>(Vw, Vt);
  k_attn<<<dim3(16, 64), 256, 0, stream>>>(Qw, Kw, Vt, out);
}

// Round 4
// 201.127 us; speedup vs baseline: 1.3992x; 1.0789x over previous
//
#include <hip/hip_runtime.h>
#include <hip/hip_bf16.h>
#include <stdint.h>

#define B_ 4
#define S_ 2048
#define D_ 1024
#define H_ 16
#define DH_ 64
#define BH_ 64
#define M_ 8192   // B_*S_

typedef __bf16 bf16;
typedef __attribute__((ext_vector_type(8))) __bf16 bf16x8;
typedef __attribute__((ext_vector_type(4))) float f32x4;
typedef __attribute__((ext_vector_type(8))) float f32x8;

#define EXP2F(x) __builtin_amdgcn_exp2f(x)

__device__ inline void gload16(const void* g, void* l) {
  __builtin_amdgcn_global_load_lds((const __attribute__((address_space(1))) void*)g,
                                   (__attribute__((address_space(3))) void*)l, 16, 0, 0);
}

// ---------------- 1. fp32 -> bf16 convert of q/k/v ----------------
__global__ __launch_bounds__(256) void k_conv(const float* __restrict__ q,
    const float* __restrict__ k, const float* __restrict__ v, bf16* __restrict__ o) {
  int z = blockIdx.y;
  const float* s = z == 0 ? q : (z == 1 ? k : v);
  bf16* d = o + (size_t)z * ((size_t)M_ * D_);
  int n8 = M_ * D_ / 8;
  for (int i = blockIdx.x * 256 + threadIdx.x; i < n8; i += gridDim.x * 256) {
    f32x8 f = ((const f32x8*)s)[i];
    bf16x8 b;
#pragma unroll
    for (int j = 0; j < 8; j++) b[j] = (bf16)f[j];
    ((bf16x8*)d)[i] = b;
  }
}

// ---------------- 2. W (DxD fp32) -> W^T (bf16) ----------------
__global__ __launch_bounds__(256) void k_wt(const float* __restrict__ wq,
    const float* __restrict__ wk, const float* __restrict__ wv, bf16* __restrict__ o) {
  __shared__ float t[32][33];
  int z = blockIdx.z;
  const float* w = z == 0 ? wq : (z == 1 ? wk : wv);
  bf16* d = o + (size_t)z * D_ * D_;
  int bn = blockIdx.x * 32;  // col (n) of W
  int bk = blockIdx.y * 32;  // row (k) of W
  int tx = threadIdx.x & 31, ty = threadIdx.x >> 5;  // 32 x 8
#pragma unroll
  for (int j = 0; j < 32; j += 8) t[ty + j][tx] = w[(size_t)(bk + ty + j) * D_ + bn + tx];
  __syncthreads();
#pragma unroll
  for (int j = 0; j < 32; j += 8)
    d[(size_t)(bn + ty + j) * D_ + bk + tx] = (bf16)t[tx][ty + j];
}

// ---------------- 3. projection GEMM: X(8192x1024) @ W -> per-head layout ----
__global__ __launch_bounds__(256) void k_proj(const bf16* __restrict__ X,
    const bf16* __restrict__ WT, bf16* __restrict__ Qo, bf16* __restrict__ Ko,
    bf16* __restrict__ Vo) {
  __shared__ bf16 lds[16384];  // A tile [128][64] elems [0,8192), B tile [8192,16384)
  int z = blockIdx.z;
  const char* Ab = (const char*)(X + (size_t)z * M_ * D_);
  const char* Bb = (const char*)(WT + (size_t)z * D_ * D_);
  int m0 = blockIdx.x * 128, n0 = blockIdx.y * 128;
  int tid = threadIdx.x, lane = tid & 63, w = tid >> 6;
  int wr = w >> 1, wc = w & 1, fr = lane & 15, fg = lane >> 4;
  f32x4 acc[4][4];
#pragma unroll
  for (int a = 0; a < 4; a++)
#pragma unroll
    for (int b = 0; b < 4; b++) acc[a][b] = (f32x4){0.f, 0.f, 0.f, 0.f};

  for (int k0 = 0; k0 < D_; k0 += 64) {
#pragma unroll
    for (int it = 0; it < 8; ++it) {
      int ow = (w + 4 * it) * 1024;   // wave-uniform LDS byte offset
      int o = ow + lane * 16;         // this lane's byte slot
      const char* src;
      if (o < 16384) {                // A region
        int row = o >> 7;
        int db = (o & 127) ^ ((row & 7) << 4);
        src = Ab + (size_t)(m0 + row) * 2048 + k0 * 2 + db;
      } else {                        // B region
        int lo = o - 16384, row = lo >> 7;
        int db = (lo & 127) ^ ((row & 7) << 4);
        src = Bb + (size_t)(n0 + row) * 2048 + k0 * 2 + db;
      }
      gload16(src, (char*)lds + ow);
    }
    __syncthreads();
#pragma unroll
    for (int c = 0; c < 2; c++) {
      bf16x8 af[4], bfr[4];
#pragma unroll
      for (int mi = 0; mi < 4; mi++) {
        int row = wr * 64 + mi * 16 + fr;
        af[mi] = *(const bf16x8*)&lds[row * 64 + ((fg * 8 + 32 * c) ^ ((row & 7) << 3))];
      }
#pragma unroll
      for (int ni = 0; ni < 4; ni++) {
        int row = wc * 64 + ni * 16 + fr;
        bfr[ni] = *(const bf16x8*)&lds[8192 + row * 64 + ((fg * 8 + 32 * c) ^ ((row & 7) << 3))];
      }
#pragma unroll
      for (int mi = 0; mi < 4; mi++)
#pragma unroll
        for (int ni = 0; ni < 4; ni++)
          acc[mi][ni] = __builtin_amdgcn_mfma_f32_16x16x32_bf16(af[mi], bfr[ni],
                                                                acc[mi][ni], 0, 0, 0);
    }
    __syncthreads();
  }
  bf16* O = z == 0 ? Qo : (z == 1 ? Ko : Vo);
  // Q: fold 1/sqrt(dh) AND log2(e) so softmax can use exp2 directly.
  float sc = (z == 0) ? 0.18033688011112042f : 1.0f;
#pragma unroll
  for (int mi = 0; mi < 4; mi++)
#pragma unroll
    for (int r = 0; r < 4; r++) {
      int row = m0 + wr * 64 + mi * 16 + 4 * fg + r;
      int b = row >> 11, s = row & 2047;
#pragma unroll
      for (int ni = 0; ni < 4; ni++) {
        int col = n0 + wc * 64 + ni * 16 + fr;
        int h = col >> 6, d = col & 63;
        O[((size_t)(b * H_ + h) * S_ + s) * DH_ + d] = (bf16)(acc[mi][ni][r] * sc);
      }
    }
}

// ---------------- 4. V [bh][s][64] -> sigma-permuted V^T [bh][64][s] --------
// Key order within each 64-block permuted by sigma: slot bits
// [c f1 f0 j2 j1 j0] -> key bits [c j2 f1 f0 j1 j0], so the attention kernel's
// PV A-fragment (P held lane-local after swapped QK^T) needs NO cross-lane ops.
__global__ __launch_bounds__(256) void k_vt(const bf16* __restrict__ V, bf16* __restrict__ VT) {
  __shared__ bf16 t[64][72];
  int bh = blockIdx.y, st = blockIdx.x * 64;
  int tid = threadIdx.x;
#pragma unroll
  for (int p = 0; p < 2; p++) {
    int idx = tid + p * 256;
    int s = idx >> 3, d0 = (idx & 7) * 8;
    *(bf16x8*)&t[s][d0] = *(const bf16x8*)(V + ((size_t)bh * S_ + st + s) * DH_ + d0);
  }
  __syncthreads();
#pragma unroll
  for (int p = 0; p < 2; p++) {
    int idx = tid + p * 256;
    int d = idx >> 3, s0 = (idx & 7) * 8;
    bf16x8 r;
#pragma unroll
    for (int j = 0; j < 8; j++) {
      int slot = s0 + j;
      int key = (slot & 0x23) | ((slot & 0x18) >> 1) | ((slot & 0x04) << 2);
      r[j] = t[key][d];
    }
    *(bf16x8*)(VT + ((size_t)bh * DH_ + d) * S_ + st + s0) = r;
  }
}

// ---------------- 5. flash attention (swapped QK^T, in-register P) ----------
// Flat grid 2048, XCD-swizzled: each XCD owns 8 complete bh.
// 4 waves x 16 q-rows (QBLK=16/wave). KBLK=64. Defer-max (T13, THR=7 log2).
// Static staging pointers: K +8192B/tile, V +128B/tile.
__global__ __launch_bounds__(256, 8) void k_attn(const bf16* __restrict__ Q,
    const bf16* __restrict__ Kt, const bf16* __restrict__ VT, float* __restrict__ out) {
  __shared__ bf16 kv[8192];     // 16KB: K tile [64][64] bytes [0,8192); V [8192,16384)
  int g = blockIdx.x;
  int wg = (g & 7) * 256 + (g >> 3);   // XCD-chunked (2048 % 8 == 0 -> bijective)
  int qt = wg & 31, bh = wg >> 5;
  int b = bh >> 4, h = bh & 15;
  int tid = threadIdx.x, lane = tid & 63, w = tid >> 6;
  int fr = lane & 15, fg = lane >> 4;
  const char* Kb = (const char*)(Kt + (size_t)bh * S_ * DH_);
  const char* Vb = (const char*)(VT + (size_t)bh * DH_ * S_);
  int q0 = qt * 64 + w * 16;

  // persistent per-lane staging sources (it=0,1 -> K; it=2,3 -> V)
  int o0 = w * 1024 + lane * 16;
  int o1 = o0 + 4096;
  int r0 = o0 >> 7, b0 = (o0 & 127) ^ ((r0 & 7) << 4);
  int r1 = o1 >> 7, b1 = (o1 & 127) ^ ((r1 & 7) << 4);
  const char* kp0 = Kb + r0 * 128 + b0;
  const char* kp1 = Kb + r1 * 128 + b1;
  const char* vp0 = Vb + r0 * 4096 + b0;
  const char* vp1 = Vb + r1 * 4096 + b1;
  char* ld0 = (char*)kv + w * 1024;

  bf16x8 qf[2];
#pragma unroll
  for (int c = 0; c < 2; c++)
    qf[c] = *(const bf16x8*)(Q + ((size_t)bh * S_ + q0 + fr) * DH_ + fg * 8 + 32 * c);
  float m_ = -1e30f, l_ = 0.f;
  f32x4 o_[4];
#pragma unroll
  for (int ds = 0; ds < 4; ds++) o_[ds] = (f32x4){0.f, 0.f, 0.f, 0.f};

  for (int kt = 0; kt < S_ / 64; ++kt) {
    gload16(kp0, ld0);
    gload16(kp1, ld0 + 4096);
    gload16(vp0, ld0 + 8192);
    gload16(vp1, ld0 + 12288);
    kp0 += 8192; kp1 += 8192; vp0 += 128; vp1 += 128;
    __syncthreads();
    // swapped QK^T: st[ks] = D[key][q], col=q=fr, key = 16ks + 4fg + r
    f32x4 st[4];
    __builtin_amdgcn_s_setprio(1);
#pragma unroll
    for (int ks = 0; ks < 4; ks++) {
      int row = ks * 16 + fr;
      bf16x8 kf0 = *(const bf16x8*)&kv[row * 64 + ((fg * 8) ^ ((row & 7) << 3))];
      bf16x8 kf1 = *(const bf16x8*)&kv[row * 64 + ((fg * 8 + 32) ^ ((row & 7) << 3))];
      f32x4 a = (f32x4){0.f, 0.f, 0.f, 0.f};
      a = __builtin_amdgcn_mfma_f32_16x16x32_bf16(kf0, qf[0], a, 0, 0, 0);
      a = __builtin_amdgcn_mfma_f32_16x16x32_bf16(kf1, qf[1], a, 0, 0, 0);
      st[ks] = a;
    }
    __builtin_amdgcn_s_setprio(0);
    // online softmax with defer-max (T13)
    float mx = st[0][0];
#pragma unroll
    for (int ks = 0; ks < 4; ks++)
#pragma unroll
      for (int r = 0; r < 4; r++) mx = fmaxf(mx, st[ks][r]);
    mx = fmaxf(mx, __shfl_xor(mx, 16));
    mx = fmaxf(mx, __shfl_xor(mx, 32));
    if (!__all(mx - m_ <= 7.0f)) {
      float mnew = fmaxf(m_, mx);
      float sf = EXP2F(m_ - mnew);
      m_ = mnew;
      l_ *= sf;
      float s0 = __shfl(sf, 4 * fg + 0);
      float s1 = __shfl(sf, 4 * fg + 1);
      float s2 = __shfl(sf, 4 * fg + 2);
      float s3 = __shfl(sf, 4 * fg + 3);
#pragma unroll
      for (int ds = 0; ds < 4; ds++) {
        o_[ds][0] *= s0; o_[ds][1] *= s1;
        o_[ds][2] *= s2; o_[ds][3] *= s3;
      }
    }
    float ps = 0.f;
#pragma unroll
    for (int ks = 0; ks < 4; ks++)
#pragma unroll
      for (int r = 0; r < 4; r++) {
        float p = EXP2F(st[ks][r] - m_);
        st[ks][r] = p;
        ps += p;
      }
    l_ += ps;
    // PV A-fragments: direct repack (sigma folded into V^T global layout)
    bf16x8 pa[2];
    pa[0] = (bf16x8){(bf16)st[0][0], (bf16)st[0][1], (bf16)st[0][2], (bf16)st[0][3],
                     (bf16)st[1][0], (bf16)st[1][1], (bf16)st[1][2], (bf16)st[1][3]};
    pa[1] = (bf16x8){(bf16)st[2][0], (bf16)st[2][1], (bf16)st[2][2], (bf16)st[2][3],
                     (bf16)st[3][0], (bf16)st[3][1], (bf16)st[3][2], (bf16)st[3][3]};
    // PV: O[q][d] += P x V
    __builtin_amdgcn_s_setprio(1);
#pragma unroll
    for (int c = 0; c < 2; c++) {
#pragma unroll
      for (int ds = 0; ds < 4; ds++) {
        int row = ds * 16 + fr;
        bf16x8 vf = *(const bf16x8*)&kv[4096 + row * 64 + ((fg * 8 + 32 * c) ^ ((row & 7) << 3))];
        o_[ds] = __builtin_amdgcn_mfma_f32_16x16x32_bf16(pa[c], vf, o_[ds], 0, 0, 0);
      }
    }
    __builtin_amdgcn_s_setprio(0);
    __syncthreads();
  }
  // finalize
  float lf = l_;
  lf += __shfl_xor(lf, 16);
  lf += __shfl_xor(lf, 32);
  float inv = 1.0f / lf;
  float ir[4];
#pragma unroll
  for (int r = 0; r < 4; r++) ir[r] = __shfl(inv, 4 * fg + r);
#pragma unroll
  for (int r = 0; r < 4; r++) {
    int s = q0 + 4 * fg + r;
#pragma unroll
    for (int ds = 0; ds < 4; ds++) {
      int col = h * DH_ + ds * 16 + fr;
      out[((size_t)b * S_ + s) * D_ + col] = o_[ds][r] * ir[r];
    }
  }
}

extern "C" void kernel_launch(void* const* d_in, const int* in_sizes, int n_in,
                              void* d_out, int out_size, void* d_ws, size_t ws_size,
                              hipStream_t stream) {
  (void)in_sizes; (void)n_in; (void)out_size; (void)ws_size;
  const float* q  = (const float*)d_in[0];
  const float* k  = (const float*)d_in[1];
  const float* v  = (const float*)d_in[2];
  const float* wq = (const float*)d_in[3];
  const float* wk = (const float*)d_in[4];
  const float* wv = (const float*)d_in[5];
  float* out = (float*)d_out;
  char* ws = (char*)d_ws;
  size_t off = 0;
  bf16* xb = (bf16*)(ws + off); off += (size_t)3 * M_ * D_ * 2;    // 50.3 MB
  bf16* wt = (bf16*)(ws + off); off += (size_t)3 * D_ * D_ * 2;    //  6.3 MB
  bf16* Qw = (bf16*)(ws + off); off += (size_t)BH_ * S_ * DH_ * 2; // 16.8 MB
  bf16* Kw = (bf16*)(ws + off); off += (size_t)BH_ * S_ * DH_ * 2;
  bf16* Vw = (bf16*)(ws + off); off += (size_t)BH_ * S_ * DH_ * 2;
  bf16* Vt = (bf16*)(ws + off); off += (size_t)BH_ * S_ * DH_ * 2;

  k_conv<<<dim3(1024, 3), 256, 0, stream>>>(q, k, v, xb);
  k_wt  <<<dim3(32, 32, 3), 256, 0, stream>>>(wq, wk, wv, wt);
  k_proj<<<dim3(64, 8, 3), 256, 0, stream>>>(xb, wt, Qw, Kw, Vw);
  k_vt  <<<dim3(32, 64), 256, 0, stream>>>(Vw, Vt);
  k_attn<<<dim3(2048), 256, 0, stream>>>(Qw, Kw, Vt, out);
}

// Round 6
// 196.345 us; speedup vs baseline: 1.4333x; 1.0244x over previous
//
#include <hip/hip_runtime.h>
#include <hip/hip_bf16.h>
#include <stdint.h>

#define B_ 4
#define S_ 2048
#define D_ 1024
#define H_ 16
#define DH_ 64
#define BH_ 64
#define M_ 8192   // B_*S_

typedef __bf16 bf16;
typedef __attribute__((ext_vector_type(8))) __bf16 bf16x8;
typedef __attribute__((ext_vector_type(4))) float f32x4;
typedef __attribute__((ext_vector_type(8))) float f32x8;

#define EXP2F(x) __builtin_amdgcn_exp2f(x)

__device__ inline void gload16(const void* g, void* l) {
  __builtin_amdgcn_global_load_lds((const __attribute__((address_space(1))) void*)g,
                                   (__attribute__((address_space(3))) void*)l, 16, 0, 0);
}

// ---------------- 1. fp32 -> bf16 convert of q/k/v ----------------
__global__ __launch_bounds__(256) void k_conv(const float* __restrict__ q,
    const float* __restrict__ k, const float* __restrict__ v, bf16* __restrict__ o) {
  int z = blockIdx.y;
  const float* s = z == 0 ? q : (z == 1 ? k : v);
  bf16* d = o + (size_t)z * ((size_t)M_ * D_);
  int n8 = M_ * D_ / 8;
  for (int i = blockIdx.x * 256 + threadIdx.x; i < n8; i += gridDim.x * 256) {
    f32x8 f = ((const f32x8*)s)[i];
    bf16x8 b;
#pragma unroll
    for (int j = 0; j < 8; j++) b[j] = (bf16)f[j];
    ((bf16x8*)d)[i] = b;
  }
}

// ---------------- 2. W (DxD fp32) -> W^T (bf16) ----------------
__global__ __launch_bounds__(256) void k_wt(const float* __restrict__ wq,
    const float* __restrict__ wk, const float* __restrict__ wv, bf16* __restrict__ o) {
  __shared__ float t[32][33];
  int z = blockIdx.z;
  const float* w = z == 0 ? wq : (z == 1 ? wk : wv);
  bf16* d = o + (size_t)z * D_ * D_;
  int bn = blockIdx.x * 32;  // col (n) of W
  int bk = blockIdx.y * 32;  // row (k) of W
  int tx = threadIdx.x & 31, ty = threadIdx.x >> 5;  // 32 x 8
#pragma unroll
  for (int j = 0; j < 32; j += 8) t[ty + j][tx] = w[(size_t)(bk + ty + j) * D_ + bn + tx];
  __syncthreads();
#pragma unroll
  for (int j = 0; j < 32; j += 8)
    d[(size_t)(bn + ty + j) * D_ + bk + tx] = (bf16)t[tx][ty + j];
}

// ---------------- 3. projection GEMM: X(8192x1024) @ W -> per-head layout ----
__global__ __launch_bounds__(256) void k_proj(const bf16* __restrict__ X,
    const bf16* __restrict__ WT, bf16* __restrict__ Qo, bf16* __restrict__ Ko,
    bf16* __restrict__ Vo) {
  __shared__ bf16 lds[16384];  // A tile [128][64] elems [0,8192), B tile [8192,16384)
  int z = blockIdx.z;
  const char* Ab = (const char*)(X + (size_t)z * M_ * D_);
  const char* Bb = (const char*)(WT + (size_t)z * D_ * D_);
  int m0 = blockIdx.x * 128, n0 = blockIdx.y * 128;
  int tid = threadIdx.x, lane = tid & 63, w = tid >> 6;
  int wr = w >> 1, wc = w & 1, fr = lane & 15, fg = lane >> 4;
  f32x4 acc[4][4];
#pragma unroll
  for (int a = 0; a < 4; a++)
#pragma unroll
    for (int b = 0; b < 4; b++) acc[a][b] = (f32x4){0.f, 0.f, 0.f, 0.f};

  for (int k0 = 0; k0 < D_; k0 += 64) {
#pragma unroll
    for (int it = 0; it < 8; ++it) {
      int ow = (w + 4 * it) * 1024;   // wave-uniform LDS byte offset
      int o = ow + lane * 16;         // this lane's byte slot
      const char* src;
      if (o < 16384) {                // A region
        int row = o >> 7;
        int db = (o & 127) ^ ((row & 7) << 4);
        src = Ab + (size_t)(m0 + row) * 2048 + k0 * 2 + db;
      } else {                        // B region
        int lo = o - 16384, row = lo >> 7;
        int db = (lo & 127) ^ ((row & 7) << 4);
        src = Bb + (size_t)(n0 + row) * 2048 + k0 * 2 + db;
      }
      gload16(src, (char*)lds + ow);
    }
    __syncthreads();
#pragma unroll
    for (int c = 0; c < 2; c++) {
      bf16x8 af[4], bfr[4];
#pragma unroll
      for (int mi = 0; mi < 4; mi++) {
        int row = wr * 64 + mi * 16 + fr;
        af[mi] = *(const bf16x8*)&lds[row * 64 + ((fg * 8 + 32 * c) ^ ((row & 7) << 3))];
      }
#pragma unroll
      for (int ni = 0; ni < 4; ni++) {
        int row = wc * 64 + ni * 16 + fr;
        bfr[ni] = *(const bf16x8*)&lds[8192 + row * 64 + ((fg * 8 + 32 * c) ^ ((row & 7) << 3))];
      }
#pragma unroll
      for (int mi = 0; mi < 4; mi++)
#pragma unroll
        for (int ni = 0; ni < 4; ni++)
          acc[mi][ni] = __builtin_amdgcn_mfma_f32_16x16x32_bf16(af[mi], bfr[ni],
                                                                acc[mi][ni], 0, 0, 0);
    }
    __syncthreads();
  }
  bf16* O = z == 0 ? Qo : (z == 1 ? Ko : Vo);
  // Q: fold 1/sqrt(dh) AND log2(e) so softmax can use exp2 directly.
  float sc = (z == 0) ? 0.18033688011112042f : 1.0f;
#pragma unroll
  for (int mi = 0; mi < 4; mi++)
#pragma unroll
    for (int r = 0; r < 4; r++) {
      int row = m0 + wr * 64 + mi * 16 + 4 * fg + r;
      int b = row >> 11, s = row & 2047;
#pragma unroll
      for (int ni = 0; ni < 4; ni++) {
        int col = n0 + wc * 64 + ni * 16 + fr;
        int h = col >> 6, d = col & 63;
        O[((size_t)(b * H_ + h) * S_ + s) * DH_ + d] = (bf16)(acc[mi][ni][r] * sc);
      }
    }
}

// ---------------- 4. V [bh][s][64] -> sigma-permuted V^T [bh][64][s] --------
// Key order within each 64-block permuted by sigma: slot bits
// [c f1 f0 j2 j1 j0] -> key bits [c j2 f1 f0 j1 j0], so the attention kernel's
// PV A-fragment (P held lane-local after swapped QK^T) needs NO cross-lane ops.
__global__ __launch_bounds__(256) void k_vt(const bf16* __restrict__ V, bf16* __restrict__ VT) {
  __shared__ bf16 t[64][72];
  int bh = blockIdx.y, st = blockIdx.x * 64;
  int tid = threadIdx.x;
#pragma unroll
  for (int p = 0; p < 2; p++) {
    int idx = tid + p * 256;
    int s = idx >> 3, d0 = (idx & 7) * 8;
    *(bf16x8*)&t[s][d0] = *(const bf16x8*)(V + ((size_t)bh * S_ + st + s) * DH_ + d0);
  }
  __syncthreads();
#pragma unroll
  for (int p = 0; p < 2; p++) {
    int idx = tid + p * 256;
    int d = idx >> 3, s0 = (idx & 7) * 8;
    bf16x8 r;
#pragma unroll
    for (int j = 0; j < 8; j++) {
      int slot = s0 + j;
      int key = (slot & 0x23) | ((slot & 0x18) >> 1) | ((slot & 0x04) << 2);
      r[j] = t[key][d];
    }
    *(bf16x8*)(VT + ((size_t)bh * DH_ + d) * S_ + st + s0) = r;
  }
}

// ---------------- 5. flash attention ----------------
// 8 waves x 16 q-rows (block = 128 q). KBLK=64, double-buffered K/V staging
// (2-phase: barrier -> STAGE(t+1, buf^1) -> compute(buf)). Online softmax with
// defer-max (T13, THR=7 in log2 domain -> p <= 2^7, round-4-validated).
// l accumulated via ones-MFMA in row form -> shuffle-free finalize.
// XCD-swizzled flat grid 1024: each XCD owns 8 complete bh.
__global__ __launch_bounds__(512, 8) void k_attn(const bf16* __restrict__ Q,
    const bf16* __restrict__ Kt, const bf16* __restrict__ VT, float* __restrict__ out) {
  __shared__ bf16 kv[16384];    // 32KB: buf0 [0,8192) K | [8192] V ; buf1 at +8192 elems
  int g = blockIdx.x;
  int wg = (g & 7) * 128 + (g >> 3);   // 1024 % 8 == 0 -> bijective
  int qt = wg & 15, bh = wg >> 4;
  int b = bh >> 4, h = bh & 15;
  int tid = threadIdx.x, lane = tid & 63, w = tid >> 6;
  int fr = lane & 15, fg = lane >> 4;
  const char* Kb = (const char*)(Kt + (size_t)bh * S_ * DH_);
  const char* Vb = (const char*)(VT + (size_t)bh * DH_ * S_);
  int q0 = qt * 128 + w * 16;

  // per-thread staging sources (512 thr x 16B = 8KB per region per round)
  int o0 = tid * 16;                       // byte offset within region [0,8192)
  int r0 = o0 >> 7, b0 = (o0 & 127) ^ ((r0 & 7) << 4);
  const char* kp = Kb + r0 * 128 + b0;     // +8192 B/tile
  const char* vp = Vb + r0 * 4096 + b0;    // +128 B/tile
  char* lb = (char*)kv;
  int w1024 = w * 1024;                    // wave-uniform LDS dest base

  bf16x8 qf[2];
#pragma unroll
  for (int c = 0; c < 2; c++)
    qf[c] = *(const bf16x8*)(Q + ((size_t)bh * S_ + q0 + fr) * DH_ + fg * 8 + 32 * c);
  float m_ = -1e30f;
  f32x4 o_[4];
#pragma unroll
  for (int ds = 0; ds < 4; ds++) o_[ds] = (f32x4){0.f, 0.f, 0.f, 0.f};
  f32x4 ol = (f32x4){0.f, 0.f, 0.f, 0.f};
  bf16x8 vones;
#pragma unroll
  for (int j = 0; j < 8; j++) vones[j] = (bf16)1.0f;

  // prologue: stage tile 0 into buf0
  gload16(kp, lb + w1024);
  gload16(vp, lb + 8192 + w1024);
  kp += 8192; vp += 128;

  for (int kt = 0; kt < 32; ++kt) {
    __syncthreads();            // drains STAGE(kt); prior reads of buf^1 done
    if (kt + 1 < 32) {          // stage next tile; lands during compute below
      int nb = ((kt + 1) & 1) << 14;
      gload16(kp, lb + nb + w1024);
      gload16(vp, lb + nb + 8192 + w1024);
      kp += 8192; vp += 128;
    }
    int cb = (kt & 1) << 13;    // current buffer, element offset
    // swapped QK^T: st[ks] = D[key][q], col=q=fr, key = 16ks + 4fg + r
    f32x4 st[4];
    __builtin_amdgcn_s_setprio(1);
#pragma unroll
    for (int ks = 0; ks < 4; ks++) {
      int row = ks * 16 + fr;
      bf16x8 kf0 = *(const bf16x8*)&kv[cb + row * 64 + ((fg * 8) ^ ((row & 7) << 3))];
      bf16x8 kf1 = *(const bf16x8*)&kv[cb + row * 64 + ((fg * 8 + 32) ^ ((row & 7) << 3))];
      f32x4 a = (f32x4){0.f, 0.f, 0.f, 0.f};
      a = __builtin_amdgcn_mfma_f32_16x16x32_bf16(kf0, qf[0], a, 0, 0, 0);
      a = __builtin_amdgcn_mfma_f32_16x16x32_bf16(kf1, qf[1], a, 0, 0, 0);
      st[ks] = a;
    }
    __builtin_amdgcn_s_setprio(0);
    // online softmax with defer-max (T13): keep p <= 2^7 (round-4-validated)
    float mx = st[0][0];
#pragma unroll
    for (int ks = 0; ks < 4; ks++)
#pragma unroll
      for (int r = 0; r < 4; r++) mx = fmaxf(mx, st[ks][r]);
    mx = fmaxf(mx, __shfl_xor(mx, 16));
    mx = fmaxf(mx, __shfl_xor(mx, 32));
    if (!__all(mx - m_ <= 7.0f)) {
      float mnew = fmaxf(m_, mx);
      float sf = EXP2F(m_ - mnew);
      m_ = mnew;
      float s0 = __shfl(sf, 4 * fg + 0);
      float s1 = __shfl(sf, 4 * fg + 1);
      float s2 = __shfl(sf, 4 * fg + 2);
      float s3 = __shfl(sf, 4 * fg + 3);
#pragma unroll
      for (int ds = 0; ds < 4; ds++) {
        o_[ds][0] *= s0; o_[ds][1] *= s1;
        o_[ds][2] *= s2; o_[ds][3] *= s3;
      }
      ol[0] *= s0; ol[1] *= s1; ol[2] *= s2; ol[3] *= s3;
    }
#pragma unroll
    for (int ks = 0; ks < 4; ks++)
#pragma unroll
      for (int r = 0; r < 4; r++) st[ks][r] = EXP2F(st[ks][r] - m_);
    bf16x8 pa[2];
    pa[0] = (bf16x8){(bf16)st[0][0], (bf16)st[0][1], (bf16)st[0][2], (bf16)st[0][3],
                     (bf16)st[1][0], (bf16)st[1][1], (bf16)st[1][2], (bf16)st[1][3]};
    pa[1] = (bf16x8){(bf16)st[2][0], (bf16)st[2][1], (bf16)st[2][2], (bf16)st[2][3],
                     (bf16)st[3][0], (bf16)st[3][1], (bf16)st[3][2], (bf16)st[3][3]};
    // PV + row-sum(l) via ones-MFMA
    __builtin_amdgcn_s_setprio(1);
    ol = __builtin_amdgcn_mfma_f32_16x16x32_bf16(pa[0], vones, ol, 0, 0, 0);
    ol = __builtin_amdgcn_mfma_f32_16x16x32_bf16(pa[1], vones, ol, 0, 0, 0);
#pragma unroll
    for (int c = 0; c < 2; c++) {
#pragma unroll
      for (int ds = 0; ds < 4; ds++) {
        int row = ds * 16 + fr;
        bf16x8 vf = *(const bf16x8*)&kv[cb + 4096 + row * 64 + ((fg * 8 + 32 * c) ^ ((row & 7) << 3))];
        o_[ds] = __builtin_amdgcn_mfma_f32_16x16x32_bf16(pa[c], vf, o_[ds], 0, 0, 0);
      }
    }
    __builtin_amdgcn_s_setprio(0);
  }
  // finalize: ol[r] = l[q=4fg+r] (replicated over fr) -> no shuffles
#pragma unroll
  for (int r = 0; r < 4; r++) {
    float inv = 1.0f / ol[r];
    int s = q0 + 4 * fg + r;
#pragma unroll
    for (int ds = 0; ds < 4; ds++) {
      int col = h * DH_ + ds * 16 + fr;
      out[((size_t)b * S_ + s) * D_ + col] = o_[ds][r] * inv;
    }
  }
}

extern "C" void kernel_launch(void* const* d_in, const int* in_sizes, int n_in,
                              void* d_out, int out_size, void* d_ws, size_t ws_size,
                              hipStream_t stream) {
  (void)in_sizes; (void)n_in; (void)out_size; (void)ws_size;
  const float* q  = (const float*)d_in[0];
  const float* k  = (const float*)d_in[1];
  const float* v  = (const float*)d_in[2];
  const float* wq = (const float*)d_in[3];
  const float* wk = (const float*)d_in[4];
  const float* wv = (const float*)d_in[5];
  float* out = (float*)d_out;
  char* ws = (char*)d_ws;
  size_t off = 0;
  bf16* xb = (bf16*)(ws + off); off += (size_t)3 * M_ * D_ * 2;    // 50.3 MB
  bf16* wt = (bf16*)(ws + off); off += (size_t)3 * D_ * D_ * 2;    //  6.3 MB
  bf16* Qw = (bf16*)(ws + off); off += (size_t)BH_ * S_ * DH_ * 2; // 16.8 MB
  bf16* Kw = (bf16*)(ws + off); off += (size_t)BH_ * S_ * DH_ * 2;
  bf16* Vw = (bf16*)(ws + off); off += (size_t)BH_ * S_ * DH_ * 2;
  bf16* Vt = (bf16*)(ws + off); off += (size_t)BH_ * S_ * DH_ * 2;

  k_conv<<<dim3(1024, 3), 256, 0, stream>>>(q, k, v, xb);
  k_wt  <<<dim3(32, 32, 3), 256, 0, stream>>>(wq, wk, wv, wt);
  k_proj<<<dim3(64, 8, 3), 256, 0, stream>>>(xb, wt, Qw, Kw, Vw);
  k_vt  <<<dim3(32, 64), 256, 0, stream>>>(Vw, Vt);
  k_attn<<<dim3(1024), 512, 0, stream>>>(Qw, Kw, Vt, out);
}

// Round 7
// 188.352 us; speedup vs baseline: 1.4941x; 1.0424x over previous
//
#include <hip/hip_runtime.h>
#include <hip/hip_bf16.h>
#include <stdint.h>

#define B_ 4
#define S_ 2048
#define D_ 1024
#define H_ 16
#define DH_ 64
#define BH_ 64
#define M_ 8192   // B_*S_

typedef __bf16 bf16;
typedef __attribute__((ext_vector_type(4))) __bf16 bf16x4;
typedef __attribute__((ext_vector_type(8))) __bf16 bf16x8;
typedef __attribute__((ext_vector_type(4))) float f32x4;
typedef __attribute__((ext_vector_type(8))) float f32x8;

#define EXP2F(x) __builtin_amdgcn_exp2f(x)

__device__ inline void gload16(const void* g, void* l) {
  __builtin_amdgcn_global_load_lds((const __attribute__((address_space(1))) void*)g,
                                   (__attribute__((address_space(3))) void*)l, 16, 0, 0);
}

// ---------------- 1. fp32 -> bf16 convert of q/k/v ----------------
__global__ __launch_bounds__(256) void k_conv(const float* __restrict__ q,
    const float* __restrict__ k, const float* __restrict__ v, bf16* __restrict__ o) {
  int z = blockIdx.y;
  const float* s = z == 0 ? q : (z == 1 ? k : v);
  bf16* d = o + (size_t)z * ((size_t)M_ * D_);
  int n8 = M_ * D_ / 8;
  for (int i = blockIdx.x * 256 + threadIdx.x; i < n8; i += gridDim.x * 256) {
    f32x8 f = ((const f32x8*)s)[i];
    bf16x8 b;
#pragma unroll
    for (int j = 0; j < 8; j++) b[j] = (bf16)f[j];
    ((bf16x8*)d)[i] = b;
  }
}

// ---------------- 2. W (DxD fp32) -> W^T (bf16) ----------------
__global__ __launch_bounds__(256) void k_wt(const float* __restrict__ wq,
    const float* __restrict__ wk, const float* __restrict__ wv, bf16* __restrict__ o) {
  __shared__ float t[32][33];
  int z = blockIdx.z;
  const float* w = z == 0 ? wq : (z == 1 ? wk : wv);
  bf16* d = o + (size_t)z * D_ * D_;
  int bn = blockIdx.x * 32;  // col (n) of W
  int bk = blockIdx.y * 32;  // row (k) of W
  int tx = threadIdx.x & 31, ty = threadIdx.x >> 5;  // 32 x 8
#pragma unroll
  for (int j = 0; j < 32; j += 8) t[ty + j][tx] = w[(size_t)(bk + ty + j) * D_ + bn + tx];
  __syncthreads();
#pragma unroll
  for (int j = 0; j < 32; j += 8)
    d[(size_t)(bn + ty + j) * D_ + bk + tx] = (bf16)t[tx][ty + j];
}

// ---------------- 3. projection GEMM: X(8192x1024) @ W -> per-head layout ----
// z=0: Q [bh][s][64] (pre-scaled log2e/8); z=1: K [bh][s][64];
// z=2: V written DIRECTLY as sigma-permuted V^T [bh][d][s] (k_vt folded in).
__global__ __launch_bounds__(256) void k_proj(const bf16* __restrict__ X,
    const bf16* __restrict__ WT, bf16* __restrict__ Qo, bf16* __restrict__ Ko,
    bf16* __restrict__ VTo) {
  __shared__ bf16 lds[16384];  // A tile [128][64] elems [0,8192), B tile [8192,16384)
  int z = blockIdx.z;
  const char* Ab = (const char*)(X + (size_t)z * M_ * D_);
  const char* Bb = (const char*)(WT + (size_t)z * D_ * D_);
  int m0 = blockIdx.x * 128, n0 = blockIdx.y * 128;
  int tid = threadIdx.x, lane = tid & 63, w = tid >> 6;
  int wr = w >> 1, wc = w & 1, fr = lane & 15, fg = lane >> 4;
  f32x4 acc[4][4];
#pragma unroll
  for (int a = 0; a < 4; a++)
#pragma unroll
    for (int b = 0; b < 4; b++) acc[a][b] = (f32x4){0.f, 0.f, 0.f, 0.f};

  for (int k0 = 0; k0 < D_; k0 += 64) {
#pragma unroll
    for (int it = 0; it < 8; ++it) {
      int ow = (w + 4 * it) * 1024;   // wave-uniform LDS byte offset
      int o = ow + lane * 16;         // this lane's byte slot
      const char* src;
      if (o < 16384) {                // A region
        int row = o >> 7;
        int db = (o & 127) ^ ((row & 7) << 4);
        src = Ab + (size_t)(m0 + row) * 2048 + k0 * 2 + db;
      } else {                        // B region
        int lo = o - 16384, row = lo >> 7;
        int db = (lo & 127) ^ ((row & 7) << 4);
        src = Bb + (size_t)(n0 + row) * 2048 + k0 * 2 + db;
      }
      gload16(src, (char*)lds + ow);
    }
    __syncthreads();
#pragma unroll
    for (int c = 0; c < 2; c++) {
      bf16x8 af[4], bfr[4];
#pragma unroll
      for (int mi = 0; mi < 4; mi++) {
        int row = wr * 64 + mi * 16 + fr;
        af[mi] = *(const bf16x8*)&lds[row * 64 + ((fg * 8 + 32 * c) ^ ((row & 7) << 3))];
      }
#pragma unroll
      for (int ni = 0; ni < 4; ni++) {
        int row = wc * 64 + ni * 16 + fr;
        bfr[ni] = *(const bf16x8*)&lds[8192 + row * 64 + ((fg * 8 + 32 * c) ^ ((row & 7) << 3))];
      }
#pragma unroll
      for (int mi = 0; mi < 4; mi++)
#pragma unroll
        for (int ni = 0; ni < 4; ni++)
          acc[mi][ni] = __builtin_amdgcn_mfma_f32_16x16x32_bf16(af[mi], bfr[ni],
                                                                acc[mi][ni], 0, 0, 0);
    }
    __syncthreads();
  }
  if (z == 2) {
    // V epilogue: VT[bh][d][blk*64 + slot], slot = sigma^-1(key); key low2 = r
    // -> 4 consecutive slots -> one 8B store per fragment.
#pragma unroll
    for (int mi = 0; mi < 4; mi++) {
      int row = m0 + wr * 64 + mi * 16 + 4 * fg;   // r = 0 base
      int bI = row >> 11, s = row & 2047;
      int blk = s >> 6, kk = s & 63;
      int slot = (kk & 0x23) | ((kk & 0x0C) << 1) | ((kk & 0x10) >> 2);
#pragma unroll
      for (int ni = 0; ni < 4; ni++) {
        int col = n0 + wc * 64 + ni * 16 + fr;
        int h = col >> 6, d = col & 63;
        bf16x4 vv = (bf16x4){(bf16)acc[mi][ni][0], (bf16)acc[mi][ni][1],
                             (bf16)acc[mi][ni][2], (bf16)acc[mi][ni][3]};
        *(bf16x4*)&VTo[((size_t)(bI * H_ + h) * DH_ + d) * S_ + blk * 64 + slot] = vv;
      }
    }
  } else {
    bf16* O = z == 0 ? Qo : Ko;
    // Q: fold 1/sqrt(dh) AND log2(e) so softmax can use exp2 directly.
    float sc = (z == 0) ? 0.18033688011112042f : 1.0f;
#pragma unroll
    for (int mi = 0; mi < 4; mi++)
#pragma unroll
      for (int r = 0; r < 4; r++) {
        int row = m0 + wr * 64 + mi * 16 + 4 * fg + r;
        int b = row >> 11, s = row & 2047;
#pragma unroll
        for (int ni = 0; ni < 4; ni++) {
          int col = n0 + wc * 64 + ni * 16 + fr;
          int h = col >> 6, d = col & 63;
          O[((size_t)(b * H_ + h) * S_ + s) * DH_ + d] = (bf16)(acc[mi][ni][r] * sc);
        }
      }
  }
}

// ---------------- 4. flash attention ----------------
// 8 waves x 16 q-rows (block = 128 q). KBLK=64, double-buffered K/V staging
// (2-phase: barrier -> STAGE(t+1, buf^1) -> compute(buf)). kt loop unrolled x2
// so buffer offsets are compile-time (addresses loop-invariant). Staging is
// UNCONDITIONAL (tile 32 reads pad garbage, never computed). Defer-max online
// softmax (THR=7); l via ones-MFMA; max tree via v_max3 fusion.
__global__ __launch_bounds__(512, 8) void k_attn(const bf16* __restrict__ Q,
    const bf16* __restrict__ Kt, const bf16* __restrict__ VT, float* __restrict__ out) {
  __shared__ bf16 kv[16384];    // 32KB: buf0 [0,8192) K | [8192] V ; buf1 at +8192 elems
  int g = blockIdx.x;
  int wg = (g & 7) * 128 + (g >> 3);   // 1024 % 8 == 0 -> bijective
  int qt = wg & 15, bh = wg >> 4;
  int b = bh >> 4, h = bh & 15;
  int tid = threadIdx.x, lane = tid & 63, w = tid >> 6;
  int fr = lane & 15, fg = lane >> 4;
  const char* Kb = (const char*)(Kt + (size_t)bh * S_ * DH_);
  const char* Vb = (const char*)(VT + (size_t)bh * DH_ * S_);
  int q0 = qt * 128 + w * 16;

  // per-thread staging sources (512 thr x 16B = 8KB per region per round)
  int o0 = tid * 16;                       // byte offset within region [0,8192)
  int r0 = o0 >> 7, b0 = (o0 & 127) ^ ((r0 & 7) << 4);
  const char* kp = Kb + r0 * 128 + b0;     // +8192 B/tile
  const char* vp = Vb + r0 * 4096 + b0;    // +128 B/tile
  char* lb = (char*)kv;
  int w1024 = w * 1024;                    // wave-uniform LDS dest base

  bf16x8 qf[2];
#pragma unroll
  for (int c = 0; c < 2; c++)
    qf[c] = *(const bf16x8*)(Q + ((size_t)bh * S_ + q0 + fr) * DH_ + fg * 8 + 32 * c);
  float m_ = -1e30f;
  f32x4 o_[4];
#pragma unroll
  for (int ds = 0; ds < 4; ds++) o_[ds] = (f32x4){0.f, 0.f, 0.f, 0.f};
  f32x4 ol = (f32x4){0.f, 0.f, 0.f, 0.f};
  bf16x8 vones;
#pragma unroll
  for (int j = 0; j < 8; j++) vones[j] = (bf16)1.0f;

  // prologue: stage tile 0 into buf0
  gload16(kp, lb + w1024);
  gload16(vp, lb + 8192 + w1024);
  kp += 8192; vp += 128;

#pragma unroll 2
  for (int kt = 0; kt < 32; ++kt) {
    __syncthreads();            // drains STAGE(kt); prior reads of buf^1 done
    {                           // stage tile kt+1 unconditionally (33rd = pad)
      const int nb = ((kt + 1) & 1) << 14;
      gload16(kp, lb + nb + w1024);
      gload16(vp, lb + nb + 8192 + w1024);
      kp += 8192; vp += 128;
    }
    const int cb = (kt & 1) << 13;   // compile-time under unroll 2
    // swapped QK^T: st[ks] = D[key][q], col=q=fr, key = 16ks + 4fg + r
    f32x4 st[4];
    __builtin_amdgcn_s_setprio(1);
#pragma unroll
    for (int ks = 0; ks < 4; ks++) {
      int row = ks * 16 + fr;
      bf16x8 kf0 = *(const bf16x8*)&kv[cb + row * 64 + ((fg * 8) ^ ((row & 7) << 3))];
      bf16x8 kf1 = *(const bf16x8*)&kv[cb + row * 64 + ((fg * 8 + 32) ^ ((row & 7) << 3))];
      f32x4 a = (f32x4){0.f, 0.f, 0.f, 0.f};
      a = __builtin_amdgcn_mfma_f32_16x16x32_bf16(kf0, qf[0], a, 0, 0, 0);
      a = __builtin_amdgcn_mfma_f32_16x16x32_bf16(kf1, qf[1], a, 0, 0, 0);
      st[ks] = a;
    }
    __builtin_amdgcn_s_setprio(0);
    // online softmax with defer-max (T13): keep p <= 2^7 (round-4-validated)
    // max tree as fmaxf triples -> v_max3_f32 fusion (T17)
    float ma = fmaxf(fmaxf(st[0][0], st[0][1]), st[0][2]);
    float mb = fmaxf(fmaxf(st[0][3], st[1][0]), st[1][1]);
    float mc = fmaxf(fmaxf(st[1][2], st[1][3]), st[2][0]);
    float md = fmaxf(fmaxf(st[2][1], st[2][2]), st[2][3]);
    float me = fmaxf(fmaxf(st[3][0], st[3][1]), st[3][2]);
    float mx = fmaxf(fmaxf(fmaxf(ma, mb), mc), fmaxf(fmaxf(md, me), st[3][3]));
    mx = fmaxf(mx, __shfl_xor(mx, 16));
    mx = fmaxf(mx, __shfl_xor(mx, 32));
    if (!__all(mx - m_ <= 7.0f)) {
      float mnew = fmaxf(m_, mx);
      float sf = EXP2F(m_ - mnew);
      m_ = mnew;
      float s0 = __shfl(sf, 4 * fg + 0);
      float s1 = __shfl(sf, 4 * fg + 1);
      float s2 = __shfl(sf, 4 * fg + 2);
      float s3 = __shfl(sf, 4 * fg + 3);
#pragma unroll
      for (int ds = 0; ds < 4; ds++) {
        o_[ds][0] *= s0; o_[ds][1] *= s1;
        o_[ds][2] *= s2; o_[ds][3] *= s3;
      }
      ol[0] *= s0; ol[1] *= s1; ol[2] *= s2; ol[3] *= s3;
    }
#pragma unroll
    for (int ks = 0; ks < 4; ks++)
#pragma unroll
      for (int r = 0; r < 4; r++) st[ks][r] = EXP2F(st[ks][r] - m_);
    bf16x8 pa[2];
    pa[0] = (bf16x8){(bf16)st[0][0], (bf16)st[0][1], (bf16)st[0][2], (bf16)st[0][3],
                     (bf16)st[1][0], (bf16)st[1][1], (bf16)st[1][2], (bf16)st[1][3]};
    pa[1] = (bf16x8){(bf16)st[2][0], (bf16)st[2][1], (bf16)st[2][2], (bf16)st[2][3],
                     (bf16)st[3][0], (bf16)st[3][1], (bf16)st[3][2], (bf16)st[3][3]};
    // PV + row-sum(l) via ones-MFMA
    __builtin_amdgcn_s_setprio(1);
    ol = __builtin_amdgcn_mfma_f32_16x16x32_bf16(pa[0], vones, ol, 0, 0, 0);
    ol = __builtin_amdgcn_mfma_f32_16x16x32_bf16(pa[1], vones, ol, 0, 0, 0);
#pragma unroll
    for (int c = 0; c < 2; c++) {
#pragma unroll
      for (int ds = 0; ds < 4; ds++) {
        int row = ds * 16 + fr;
        bf16x8 vf = *(const bf16x8*)&kv[cb + 4096 + row * 64 + ((fg * 8 + 32 * c) ^ ((row & 7) << 3))];
        o_[ds] = __builtin_amdgcn_mfma_f32_16x16x32_bf16(pa[c], vf, o_[ds], 0, 0, 0);
      }
    }
    __builtin_amdgcn_s_setprio(0);
  }
  // finalize: ol[r] = l[q=4fg+r] (replicated over fr) -> no shuffles
#pragma unroll
  for (int r = 0; r < 4; r++) {
    float inv = 1.0f / ol[r];
    int s = q0 + 4 * fg + r;
#pragma unroll
    for (int ds = 0; ds < 4; ds++) {
      int col = h * DH_ + ds * 16 + fr;
      out[((size_t)b * S_ + s) * D_ + col] = o_[ds][r] * inv;
    }
  }
}

extern "C" void kernel_launch(void* const* d_in, const int* in_sizes, int n_in,
                              void* d_out, int out_size, void* d_ws, size_t ws_size,
                              hipStream_t stream) {
  (void)in_sizes; (void)n_in; (void)out_size; (void)ws_size;
  const float* q  = (const float*)d_in[0];
  const float* k  = (const float*)d_in[1];
  const float* v  = (const float*)d_in[2];
  const float* wq = (const float*)d_in[3];
  const float* wk = (const float*)d_in[4];
  const float* wv = (const float*)d_in[5];
  float* out = (float*)d_out;
  char* ws = (char*)d_ws;
  size_t off = 0;
  bf16* xb = (bf16*)(ws + off); off += (size_t)3 * M_ * D_ * 2;    // 50.3 MB
  bf16* wt = (bf16*)(ws + off); off += (size_t)3 * D_ * D_ * 2;    //  6.3 MB
  bf16* Qw = (bf16*)(ws + off); off += (size_t)BH_ * S_ * DH_ * 2; // 16.8 MB
  bf16* Kw = (bf16*)(ws + off); off += (size_t)BH_ * S_ * DH_ * 2;
  bf16* Vt = (bf16*)(ws + off); off += (size_t)BH_ * S_ * DH_ * 2;
  // tail pad (>= 16 MB): attn's unconditional 33rd-tile prefetch reads
  // up to ~8KB past Kw (lands in Vt) and past Vt (lands here). Never used.

  k_conv<<<dim3(1024, 3), 256, 0, stream>>>(q, k, v, xb);
  k_wt  <<<dim3(32, 32, 3), 256, 0, stream>>>(wq, wk, wv, wt);
  k_proj<<<dim3(64, 8, 3), 256, 0, stream>>>(xb, wt, Qw, Kw, Vt);
  k_attn<<<dim3(1024), 512, 0, stream>>>(Qw, Kw, Vt, out);
}